// Round 1
// baseline (98.358 us; speedup 1.0000x reference)
//
#include <hip/hip_runtime.h>
#include <hip/hip_bf16.h>

// Problem constants
#define L_SEQ   4096
#define D_IN    1024
#define N_BATCH 16
#define L_OUT   1024
#define D_OUT   1024
#define M_DIM   (N_BATCH * L_OUT)   // 16384

// GEMM tiling
#define BM 128
#define BN 128
#define BK 32
#define LDSS 40   // LDS row stride in bf16 elems (32 + 8 pad; 80B, 16B-aligned)

typedef __attribute__((ext_vector_type(4))) float  f32x4;
typedef __attribute__((ext_vector_type(8))) __bf16 bf16x8;
typedef __attribute__((ext_vector_type(4))) __bf16 bf16x4;

// ---------------------------------------------------------------------------
// Kernel 1: s[b] = min(sum(attention_mask[b,:]), L_OUT)
// ---------------------------------------------------------------------------
__global__ __launch_bounds__(256) void mask_sum_kernel(
    const int* __restrict__ mask, int* __restrict__ s_out)
{
    const int b = blockIdx.x;
    const int t = threadIdx.x;
    const int* row = mask + (size_t)b * L_SEQ;

    int sum = 0;
#pragma unroll
    for (int i = 0; i < L_SEQ / 256; ++i) sum += row[t + i * 256];

    // wave reduce (64 lanes)
#pragma unroll
    for (int off = 32; off > 0; off >>= 1) sum += __shfl_down(sum, off, 64);

    __shared__ int wsum[4];
    if ((t & 63) == 0) wsum[t >> 6] = sum;
    __syncthreads();
    if (t == 0) {
        int total = wsum[0] + wsum[1] + wsum[2] + wsum[3];
        s_out[b] = total < L_OUT ? total : L_OUT;
    }
}

// ---------------------------------------------------------------------------
// Kernel 2: C[m,n] = sum_k A[m,k] * W[n,k] + bias[n]
//   A[b*1024 + j, k] = (j < s_b) ? x[b, L - s_b + j, k] : 0   (cast to bf16)
// 128x128 tile, BK=32, 4 waves (2x2), 16x16x32 bf16 MFMA, 4x4 frags/wave.
// Staging: fp32 float4 global loads -> cvt bf16 -> ds_write_b64, with
// next-slab loads issued before the MFMA phase (latency hidden under compute).
// ---------------------------------------------------------------------------
__global__ __launch_bounds__(256) void gemm_restrict_kernel(
    const float* __restrict__ x,     // (16, 4096, 1024)
    const float* __restrict__ W,     // (1024, 1024)
    const float* __restrict__ bias,  // (1024,)
    const int*   __restrict__ s_arr, // (16,)
    float* __restrict__ out)         // (16384, 1024)
{
    __shared__ __bf16 As[BM][LDSS];
    __shared__ __bf16 Bs[BN][LDSS];

    const int tid    = threadIdx.x;
    const int bx     = blockIdx.x;
    const int tile_n = bx & 7;        // N/BN = 8
    const int tile_m = bx >> 3;       // M/BM = 128
    const int lane   = tid & 63;
    const int wave   = tid >> 6;
    const int wm     = wave >> 1;     // 0..1
    const int wn     = wave & 1;      // 0..1

    // staging assignment: rows sr, sr+32, sr+64, sr+96 ; cols [sc, sc+4)
    const int sr = tid >> 3;          // 0..31
    const int sc = (tid & 7) * 4;     // 0..28

    // batch for this M-tile (128 | 1024, so a tile never crosses batches)
    const int bb = tile_m >> 3;
    const int s  = s_arr[bb];
    const float* xb = x + (size_t)bb * L_SEQ * D_IN;

    const float* a_src[4];
    bool a_ok[4];
#pragma unroll
    for (int i = 0; i < 4; ++i) {
        int lr  = (tile_m * BM + sr + 32 * i) & (L_OUT - 1);
        a_ok[i] = (lr < s);
        int xr  = a_ok[i] ? (L_SEQ - s + lr) : 0;
        a_src[i] = xb + (size_t)xr * D_IN + sc;
    }
    const float* b_src[4];
#pragma unroll
    for (int i = 0; i < 4; ++i) {
        int nr = tile_n * BN + sr + 32 * i;   // W row == output col
        b_src[i] = W + (size_t)nr * D_IN + sc;
    }

    f32x4 acc[4][4];
#pragma unroll
    for (int i = 0; i < 4; ++i)
#pragma unroll
        for (int j = 0; j < 4; ++j) acc[i][j] = (f32x4){0.f, 0.f, 0.f, 0.f};

    const f32x4 zf = {0.f, 0.f, 0.f, 0.f};
    const int fr   = lane & 15;          // fragment row (A) / col (B)
    const int koff = (lane >> 4) * 8;    // k offset within BK

    // prologue: loads for kt = 0
    f32x4 ra[4], rb[4];
#pragma unroll
    for (int i = 0; i < 4; ++i) {
        ra[i] = a_ok[i] ? *(const f32x4*)(a_src[i]) : zf;
        rb[i] = *(const f32x4*)(b_src[i]);
    }

    const int NKT = D_IN / BK;  // 32
    for (int kt = 0; kt < NKT; ++kt) {
        __syncthreads();  // previous iteration's ds_reads complete

        // cvt + LDS write of current slab
#pragma unroll
        for (int i = 0; i < 4; ++i) {
            bf16x4 av = {(__bf16)ra[i].x, (__bf16)ra[i].y,
                         (__bf16)ra[i].z, (__bf16)ra[i].w};
            *(bf16x4*)&As[sr + 32 * i][sc] = av;
            bf16x4 bv = {(__bf16)rb[i].x, (__bf16)rb[i].y,
                         (__bf16)rb[i].z, (__bf16)rb[i].w};
            *(bf16x4*)&Bs[sr + 32 * i][sc] = bv;
        }

        // issue next slab's global loads (hidden under MFMA phase)
        if (kt + 1 < NKT) {
            const int off = (kt + 1) * BK;
#pragma unroll
            for (int i = 0; i < 4; ++i) {
                ra[i] = a_ok[i] ? *(const f32x4*)(a_src[i] + off) : zf;
                rb[i] = *(const f32x4*)(b_src[i] + off);
            }
        }

        __syncthreads();  // LDS tile ready

        bf16x8 af[4], bfr[4];
#pragma unroll
        for (int i = 0; i < 4; ++i)
            af[i] = *(const bf16x8*)&As[wm * 64 + i * 16 + fr][koff];
#pragma unroll
        for (int j = 0; j < 4; ++j)
            bfr[j] = *(const bf16x8*)&Bs[wn * 64 + j * 16 + fr][koff];

#pragma unroll
        for (int i = 0; i < 4; ++i)
#pragma unroll
            for (int j = 0; j < 4; ++j)
                acc[i][j] = __builtin_amdgcn_mfma_f32_16x16x32_bf16(
                    af[i], bfr[j], acc[i][j], 0, 0, 0);
    }

    // epilogue: bias + store
    float bias_v[4];
#pragma unroll
    for (int j = 0; j < 4; ++j)
        bias_v[j] = bias[tile_n * BN + wn * 64 + j * 16 + fr];

    const int crow = tile_m * BM + wm * 64 + (lane >> 4) * 4;
    const int ccol = tile_n * BN + wn * 64 + fr;
#pragma unroll
    for (int i = 0; i < 4; ++i) {
#pragma unroll
        for (int j = 0; j < 4; ++j) {
#pragma unroll
            for (int r = 0; r < 4; ++r) {
                int row = crow + i * 16 + r;
                int col = ccol + j * 16;
                out[(size_t)row * D_OUT + col] = acc[i][j][r] + bias_v[j];
            }
        }
    }
}

// ---------------------------------------------------------------------------
extern "C" void kernel_launch(void* const* d_in, const int* in_sizes, int n_in,
                              void* d_out, int out_size, void* d_ws, size_t ws_size,
                              hipStream_t stream) {
    const float* x    = (const float*)d_in[0];
    const int*   mask = (const int*)d_in[1];
    const float* W    = (const float*)d_in[2];
    const float* bias = (const float*)d_in[3];
    float*       out  = (float*)d_out;
    int*         s_arr = (int*)d_ws;   // 16 ints

    mask_sum_kernel<<<dim3(N_BATCH), dim3(256), 0, stream>>>(mask, s_arr);

    const int grid = (M_DIM / BM) * (D_OUT / BN);  // 128 * 8 = 1024
    gemm_restrict_kernel<<<dim3(grid), dim3(256), 0, stream>>>(
        x, W, bias, s_arr, out);
}

// Round 2
// 81.733 us; speedup vs baseline: 1.2034x; 1.2034x over previous
//
#include <hip/hip_runtime.h>
#include <hip/hip_bf16.h>

// Problem constants
#define L_SEQ   4096
#define D_IN    1024
#define N_BATCH 16
#define L_OUT   1024
#define D_OUT   1024
#define M_DIM   (N_BATCH * L_OUT)   // 16384
#define K_DIM   D_IN

// GEMM tiling
#define BM 128
#define BN 128
#define BK 64

typedef __attribute__((ext_vector_type(4))) float  f32x4;
typedef __attribute__((ext_vector_type(8))) __bf16 bf16x8;
typedef __attribute__((ext_vector_type(4))) __bf16 bf16x4;

// ws layout (bytes)
#define WS_A_OFF 0u
#define WS_W_OFF (32u * 1024u * 1024u)                  // 32 MiB
#define WS_S_OFF (WS_W_OFF + 2u * 1024u * 1024u)       // +2 MiB

// ---------------------------------------------------------------------------
// Kernel 1: s[b] = min(sum(attention_mask[b,:]), L_OUT)
// ---------------------------------------------------------------------------
__global__ __launch_bounds__(256) void mask_sum_kernel(
    const int* __restrict__ mask, int* __restrict__ s_out)
{
    const int b = blockIdx.x;
    const int t = threadIdx.x;
    const int* row = mask + (size_t)b * L_SEQ;

    int sum = 0;
#pragma unroll
    for (int i = 0; i < L_SEQ / 256; ++i) sum += row[t + i * 256];

#pragma unroll
    for (int off = 32; off > 0; off >>= 1) sum += __shfl_down(sum, off, 64);

    __shared__ int wsum[4];
    if ((t & 63) == 0) wsum[t >> 6] = sum;
    __syncthreads();
    if (t == 0) {
        int total = wsum[0] + wsum[1] + wsum[2] + wsum[3];
        s_out[b] = total < L_OUT ? total : L_OUT;
    }
}

// ---------------------------------------------------------------------------
// Kernel 2: build bf16 A (restricted+zero-padded) and bf16 W in ws,
// PRE-SWIZZLED per row: elem e stored at (e & ~63) | ((e & 63) ^ ((row&7)<<3)).
// This makes the GEMM's linear-dest global_load_lds produce an LDS layout
// whose ds_read_b128 (with the same XOR applied) is bank-conflict-free.
// Grid: rows 0..16383 -> A, rows 16384..17407 -> W. One row per block.
// ---------------------------------------------------------------------------
__global__ __launch_bounds__(256) void convert_kernel(
    const float* __restrict__ x,     // (16, 4096, 1024)
    const float* __restrict__ W,     // (1024, 1024)
    const int*   __restrict__ s_arr, // (16,)
    __bf16* __restrict__ wsA,        // (16384, 1024)
    __bf16* __restrict__ wsW)        // (1024, 1024)
{
    const int rid = blockIdx.x;
    const int t   = threadIdx.x;
    const int e0  = t * 4;                       // 4 elems/thread
    const int swz = 0;                            // placeholder

    if (rid < M_DIM) {
        const int b = rid >> 10;
        const int j = rid & (L_OUT - 1);
        const int s = s_arr[b];
        const int rsw = (rid & 7) << 3;
        const int dste = (e0 & ~63) | ((e0 & 63) ^ rsw);
        __bf16* dst = wsA + (size_t)rid * K_DIM + dste;
        if (j < s) {
            const float* src = x + ((size_t)b * L_SEQ + (L_SEQ - s + j)) * D_IN + e0;
            f32x4 v = *(const f32x4*)src;
            bf16x4 o = {(__bf16)v.x, (__bf16)v.y, (__bf16)v.z, (__bf16)v.w};
            *(bf16x4*)dst = o;
        } else {
            bf16x4 o = {(__bf16)0.f, (__bf16)0.f, (__bf16)0.f, (__bf16)0.f};
            *(bf16x4*)dst = o;
        }
    } else {
        const int n = rid - M_DIM;               // 0..1023
        const int rsw = (n & 7) << 3;
        const int dste = (e0 & ~63) | ((e0 & 63) ^ rsw);
        const float* src = W + (size_t)n * D_IN + e0;
        f32x4 v = *(const f32x4*)src;
        bf16x4 o = {(__bf16)v.x, (__bf16)v.y, (__bf16)v.z, (__bf16)v.w};
        *(bf16x4*)(wsW + (size_t)n * K_DIM + dste) = o;
    }
    (void)swz;
}

// ---------------------------------------------------------------------------
// Kernel 3: GEMM  out[m,n] = sum_k A[m,k]*W[n,k] + bias[n]   (A,W bf16 in ws)
// m97 structure: 128x128 tile, BK=64, 4 waves (2x2), 16x16x32 bf16 MFMA,
// global_load_lds width=16 staging, 2 barriers per K-step.
// LDS holds the swizzled layout; ds_read applies elem ^= (row&7)<<3.
// ---------------------------------------------------------------------------
__device__ __forceinline__ void gload16(const __bf16* g, __bf16* l) {
    __builtin_amdgcn_global_load_lds(
        (const __attribute__((address_space(1))) void*)g,
        (__attribute__((address_space(3))) void*)l,
        16, 0, 0);
}

__global__ __launch_bounds__(256) void gemm_kernel(
    const __bf16* __restrict__ A,    // (16384, 1024) swizzled rows
    const __bf16* __restrict__ Wb,   // (1024, 1024) swizzled rows
    const float*  __restrict__ bias, // (1024,)
    float* __restrict__ out)         // (16384, 1024)
{
    __shared__ __bf16 As[BM * BK];   // 16 KiB
    __shared__ __bf16 Bs[BN * BK];   // 16 KiB

    const int tid    = threadIdx.x;
    const int bx     = blockIdx.x;
    const int tile_n = bx & 7;        // N/BN = 8
    const int tile_m = bx >> 3;       // M/BM = 128
    const int lane   = tid & 63;
    const int wave   = tid >> 6;
    const int wm     = wave >> 1;     // 0..1
    const int wn     = wave & 1;      // 0..1

    // staging: chunk q covers rows q*8..q*8+7, 1 KiB each. wave handles q=wave*4+c.
    // lane l: row q*8 + (l>>3), byte col (l&7)*16  == LDS base + l*16 (linear).
    const int srow = lane >> 3;       // 0..7
    const int scol = (lane & 7) * 8;  // elem col 0..56

    const __bf16* a_src[4];
    const __bf16* b_src[4];
#pragma unroll
    for (int c = 0; c < 4; ++c) {
        const int q = wave * 4 + c;
        a_src[c] = A  + (size_t)(tile_m * BM + q * 8 + srow) * K_DIM + scol;
        b_src[c] = Wb + (size_t)(tile_n * BN + q * 8 + srow) * K_DIM + scol;
    }

    f32x4 acc[4][4];
#pragma unroll
    for (int i = 0; i < 4; ++i)
#pragma unroll
        for (int j = 0; j < 4; ++j) acc[i][j] = (f32x4){0.f, 0.f, 0.f, 0.f};

    const int fr    = lane & 15;          // fragment row (A) / col (B)
    const int koff8 = (lane >> 4) * 8;    // k sub-offset
    const int swz   = (fr & 7) << 3;      // read-side XOR (elems)

    const int NKT = K_DIM / BK;  // 16
    for (int kt = 0; kt < NKT; ++kt) {
        // stage slab kt (A: 16 KiB, B: 16 KiB), linear LDS dest
#pragma unroll
        for (int c = 0; c < 4; ++c) {
            const int q = wave * 4 + c;
            gload16(a_src[c] + kt * BK, &As[q * 512]);
            gload16(b_src[c] + kt * BK, &Bs[q * 512]);
        }
        __syncthreads();   // drains vmcnt(0): LDS slab ready

        bf16x8 af[2][4], bf[2][4];
#pragma unroll
        for (int kk = 0; kk < 2; ++kk) {
            const int kc = (kk * 32 + koff8) ^ swz;
#pragma unroll
            for (int i = 0; i < 4; ++i)
                af[kk][i] = *(const bf16x8*)&As[(wm * 64 + i * 16 + fr) * BK + kc];
#pragma unroll
            for (int j = 0; j < 4; ++j)
                bf[kk][j] = *(const bf16x8*)&Bs[(wn * 64 + j * 16 + fr) * BK + kc];
#pragma unroll
            for (int i = 0; i < 4; ++i)
#pragma unroll
                for (int j = 0; j < 4; ++j)
                    acc[i][j] = __builtin_amdgcn_mfma_f32_16x16x32_bf16(
                        af[kk][i], bf[kk][j], acc[i][j], 0, 0, 0);
        }
        __syncthreads();   // all waves done reading before next overwrite
    }

    // epilogue: bias + store
    float bias_v[4];
#pragma unroll
    for (int j = 0; j < 4; ++j)
        bias_v[j] = bias[tile_n * BN + wn * 64 + j * 16 + fr];

    const int crow = tile_m * BM + wm * 64 + (lane >> 4) * 4;
    const int ccol = tile_n * BN + wn * 64 + fr;
#pragma unroll
    for (int i = 0; i < 4; ++i)
#pragma unroll
        for (int j = 0; j < 4; ++j)
#pragma unroll
            for (int r = 0; r < 4; ++r)
                out[(size_t)(crow + i * 16 + r) * D_OUT + (ccol + j * 16)] =
                    acc[i][j][r] + bias_v[j];
}

// ---------------------------------------------------------------------------
extern "C" void kernel_launch(void* const* d_in, const int* in_sizes, int n_in,
                              void* d_out, int out_size, void* d_ws, size_t ws_size,
                              hipStream_t stream) {
    const float* x    = (const float*)d_in[0];
    const int*   mask = (const int*)d_in[1];
    const float* W    = (const float*)d_in[2];
    const float* bias = (const float*)d_in[3];
    float*       out  = (float*)d_out;

    __bf16* wsA  = (__bf16*)((char*)d_ws + WS_A_OFF);
    __bf16* wsW  = (__bf16*)((char*)d_ws + WS_W_OFF);
    int*    s_arr = (int*)((char*)d_ws + WS_S_OFF);

    mask_sum_kernel<<<dim3(N_BATCH), dim3(256), 0, stream>>>(mask, s_arr);

    convert_kernel<<<dim3(M_DIM + D_OUT), dim3(256), 0, stream>>>(
        x, W, s_arr, wsA, wsW);

    const int grid = (M_DIM / BM) * (D_OUT / BN);  // 128 * 8 = 1024
    gemm_kernel<<<dim3(grid), dim3(256), 0, stream>>>(wsA, wsW, bias, out);
}

// Round 4
// 63.982 us; speedup vs baseline: 1.5373x; 1.2774x over previous
//
#include <hip/hip_runtime.h>
#include <hip/hip_bf16.h>

// Problem constants
#define L_SEQ   4096
#define D_IN    1024
#define N_BATCH 16
#define L_OUT   1024
#define D_OUT   1024
#define M_DIM   (N_BATCH * L_OUT)   // 16384
#define K_DIM   D_IN

// GEMM tiling (256x256 8-phase template)
#define BM 256
#define BN 256
#define BK 64
#define NKT (K_DIM / BK)   // 16

typedef __attribute__((ext_vector_type(4))) float  f32x4;
typedef __attribute__((ext_vector_type(8))) __bf16 bf16x8;
typedef __attribute__((ext_vector_type(4))) __bf16 bf16x4;

// ws layout (bytes)
#define WS_A_OFF 0u
#define WS_W_OFF (32u * 1024u * 1024u)
#define WS_S_OFF (WS_W_OFF + 2u * 1024u * 1024u)

// ---------------------------------------------------------------------------
// Kernel 1: s[b] = min(sum(attention_mask[b,:]), L_OUT)
// ---------------------------------------------------------------------------
__global__ __launch_bounds__(256) void mask_sum_kernel(
    const int* __restrict__ mask, int* __restrict__ s_out)
{
    const int b = blockIdx.x;
    const int t = threadIdx.x;
    const int* row = mask + (size_t)b * L_SEQ;

    int sum = 0;
#pragma unroll
    for (int i = 0; i < L_SEQ / 256; ++i) sum += row[t + i * 256];

#pragma unroll
    for (int off = 32; off > 0; off >>= 1) sum += __shfl_down(sum, off, 64);

    __shared__ int wsum[4];
    if ((t & 63) == 0) wsum[t >> 6] = sum;
    __syncthreads();
    if (t == 0) {
        int total = wsum[0] + wsum[1] + wsum[2] + wsum[3];
        s_out[b] = total < L_OUT ? total : L_OUT;
    }
}

// ---------------------------------------------------------------------------
// Kernel 2: build bf16 A (restricted+zero-padded) and bf16 W in ws,
// pre-swizzled per row: elem e -> (e & ~63) | ((e & 63) ^ ((row&7)<<3)).
// GEMM stages with LINEAR source columns (content already permuted) and
// linear-dest global_load_lds; the ds_read side applies the same XOR.
// ---------------------------------------------------------------------------
__global__ __launch_bounds__(256) void convert_kernel(
    const float* __restrict__ x,     // (16, 4096, 1024)
    const float* __restrict__ W,     // (1024, 1024)
    const int*   __restrict__ s_arr, // (16,)
    __bf16* __restrict__ wsA,        // (16384, 1024)
    __bf16* __restrict__ wsW)        // (1024, 1024)
{
    const int rid = blockIdx.x;
    const int t   = threadIdx.x;
    const int e0  = t * 4;

    if (rid < M_DIM) {
        const int b = rid >> 10;
        const int j = rid & (L_OUT - 1);
        const int s = s_arr[b];
        const int rsw  = (rid & 7) << 3;
        const int dste = (e0 & ~63) | ((e0 & 63) ^ rsw);
        __bf16* dst = wsA + (size_t)rid * K_DIM + dste;
        if (j < s) {
            const float* src = x + ((size_t)b * L_SEQ + (L_SEQ - s + j)) * D_IN + e0;
            f32x4 v = *(const f32x4*)src;
            bf16x4 o = {(__bf16)v.x, (__bf16)v.y, (__bf16)v.z, (__bf16)v.w};
            *(bf16x4*)dst = o;
        } else {
            bf16x4 o = {(__bf16)0.f, (__bf16)0.f, (__bf16)0.f, (__bf16)0.f};
            *(bf16x4*)dst = o;
        }
    } else {
        const int n = rid - M_DIM;
        const int rsw  = (n & 7) << 3;
        const int dste = (e0 & ~63) | ((e0 & 63) ^ rsw);
        const float* src = W + (size_t)n * D_IN + e0;
        f32x4 v = *(const f32x4*)src;
        bf16x4 o = {(__bf16)v.x, (__bf16)v.y, (__bf16)v.z, (__bf16)v.w};
        *(bf16x4*)(wsW + (size_t)n * K_DIM + dste) = o;
    }
}

// ---------------------------------------------------------------------------
// Kernel 3: 256x256 8-phase GEMM.  out[m,n] = sum_k A[m,k]*W[n,k] + bias[n]
// 8 waves (2M x 4N), per-wave out 128x64, acc[8][4] f32x4.
// Double-buffered LDS (128 KiB), half-tile (128x64) stage granularity,
// counted vmcnt (never 0 in steady state), setprio around MFMA clusters.
// Per-thread load ledger (verified): buf(kt) = {kt-2:P3,P4 ; kt-1:P1};
// at kt's P1 the 4 newest outstanding are kt-1:P3,P4 -> vmcnt(4) is exact.
// ---------------------------------------------------------------------------
__device__ __forceinline__ void gload16(const __bf16* g, __bf16* l) {
    __builtin_amdgcn_global_load_lds(
        (const __attribute__((address_space(1))) void*)g,
        (__attribute__((address_space(3))) void*)l,
        16, 0, 0);
}

#define FENCE() asm volatile("" ::: "memory")

__global__ __launch_bounds__(512, 2) void gemm_kernel(
    const __bf16* __restrict__ A,    // (16384, 1024) swizzled rows
    const __bf16* __restrict__ Wb,   // (1024, 1024)  swizzled rows
    const float*  __restrict__ bias, // (1024,)
    float* __restrict__ out)         // (16384, 1024)
{
    __shared__ __bf16 smem[2][2][BM * BK];   // 128 KiB

    const int t  = threadIdx.x;       // 0..511
    const int bx = blockIdx.x;        // 256 blocks
    const int tile_n = bx & 3;        // N/BN = 4
    const int tile_m = bx >> 2;       // M/BM = 64
    const int m0 = tile_m * BM;
    const int n0 = tile_n * BN;
    const int lane = t & 63;
    const int wave = t >> 6;
    const int wm = wave >> 2;         // 0..1
    const int wn = wave & 3;          // 0..3

    // staging geometry: per gload round, 64 rows x 64 cols; LINEAR src cols
    // (ws content is already swizzled; LDS inherits the swizzled layout).
    const int srow = t >> 3;          // 0..63
    const int scol = (t & 7) * 8;     // linear source elem col
    const int sdst = (t & 7) * 8;     // linear LDS elem col

    const __bf16* Ag = A  + (size_t)m0 * K_DIM;
    const __bf16* Bg = Wb + (size_t)n0 * K_DIM;

#define STAGE_HALF(gbase, lbase, h, kt_)                                   \
    {                                                                      \
        _Pragma("unroll")                                                  \
        for (int rd = 0; rd < 2; ++rd) {                                   \
            const int r_ = (h) * 128 + rd * 64 + srow;                     \
            gload16((gbase) + (size_t)r_ * K_DIM + (kt_) * BK + scol,      \
                    (lbase) + r_ * BK + sdst);                             \
        }                                                                  \
    }

    // fragment read geometry
    const int fr  = lane & 15;
    const int k8  = (lane >> 4) * 8;
    const int swz = (fr & 7) << 3;
    const int kc0 = k8 ^ swz;
    const int kc1 = (32 + k8) ^ swz;

    bf16x8 aF[4][2], bF0[2][2], bF1[2][2];
    f32x4 acc[8][4];
#pragma unroll
    for (int f = 0; f < 8; ++f)
#pragma unroll
        for (int g = 0; g < 4; ++g) acc[f][g] = (f32x4){0.f, 0.f, 0.f, 0.f};

#define LOAD_AF(Ac, mh)                                                    \
    {                                                                      \
        const __bf16* rb_ = (Ac) + (wm * 128 + (mh) * 64 + fr) * BK;       \
        _Pragma("unroll")                                                  \
        for (int i = 0; i < 4; ++i) {                                      \
            aF[i][0] = *(const bf16x8*)&rb_[i * 16 * BK + kc0];            \
            aF[i][1] = *(const bf16x8*)&rb_[i * 16 * BK + kc1];            \
        }                                                                  \
    }

#define LOAD_BF(Bc, nh, bF)                                                \
    {                                                                      \
        const __bf16* rb_ = (Bc) + (wn * 64 + (nh) * 32 + fr) * BK;        \
        _Pragma("unroll")                                                  \
        for (int j = 0; j < 2; ++j) {                                      \
            bF[j][0] = *(const bf16x8*)&rb_[j * 16 * BK + kc0];            \
            bF[j][1] = *(const bf16x8*)&rb_[j * 16 * BK + kc1];            \
        }                                                                  \
    }

#define MFMA_QUAD(mh, nh, bF)                                              \
    {                                                                      \
        _Pragma("unroll")                                                  \
        for (int i = 0; i < 4; ++i)                                        \
            _Pragma("unroll")                                              \
            for (int j = 0; j < 2; ++j) {                                  \
                f32x4 c_ = acc[(mh) * 4 + i][(nh) * 2 + j];                \
                c_ = __builtin_amdgcn_mfma_f32_16x16x32_bf16(              \
                    aF[i][0], bF[j][0], c_, 0, 0, 0);                      \
                c_ = __builtin_amdgcn_mfma_f32_16x16x32_bf16(              \
                    aF[i][1], bF[j][1], c_, 0, 0, 0);                      \
                acc[(mh) * 4 + i][(nh) * 2 + j] = c_;                      \
            }                                                              \
    }

    // prologue: A0(0), B0h1(0), A0h1... order fixes the vmcnt ledger:
    // loads 1-8 = full buf0(kt=0); 9-12 = A(1)h0, B(1)h1.
    {
        __bf16* A0l = &smem[0][0][0];
        __bf16* B0l = &smem[0][1][0];
        __bf16* A1l = &smem[1][0][0];
        __bf16* B1l = &smem[1][1][0];
        STAGE_HALF(Ag, A0l, 0, 0);
        STAGE_HALF(Bg, B0l, 1, 0);
        STAGE_HALF(Ag, A0l, 1, 0);
        STAGE_HALF(Bg, B0l, 0, 0);
        STAGE_HALF(Ag, A1l, 0, 1);
        STAGE_HALF(Bg, B1l, 1, 1);
    }

    for (int kt = 0; kt < NKT; ++kt) {
        const int cur = kt & 1;
        __bf16* Ac = &smem[cur][0][0];
        __bf16* Bc = &smem[cur][1][0];
        __bf16* An = &smem[cur ^ 1][0][0];
        __bf16* Bn = &smem[cur ^ 1][1][0];

        // ---- P1: quadrant (0,0) ----
        FENCE();
        if (kt == NKT - 1) asm volatile("s_waitcnt vmcnt(0)" ::: "memory");
        else               asm volatile("s_waitcnt vmcnt(4)" ::: "memory");
        __builtin_amdgcn_s_barrier();
        FENCE();
        LOAD_AF(Ac, 0);
        LOAD_BF(Bc, 0, bF0);
        if (kt + 1 < NKT) {
            STAGE_HALF(Ag, An, 1, kt + 1);
            STAGE_HALF(Bg, Bn, 0, kt + 1);
        }
        asm volatile("s_waitcnt lgkmcnt(0)" ::: "memory");
        __builtin_amdgcn_sched_barrier(0);
        __builtin_amdgcn_s_setprio(1);
        MFMA_QUAD(0, 0, bF0);
        __builtin_amdgcn_s_setprio(0);

        // ---- P2: quadrant (0,1) ----
        FENCE();
        __builtin_amdgcn_s_barrier();
        FENCE();
        LOAD_BF(Bc, 1, bF1);
        asm volatile("s_waitcnt lgkmcnt(0)" ::: "memory");
        __builtin_amdgcn_sched_barrier(0);
        __builtin_amdgcn_s_setprio(1);
        MFMA_QUAD(0, 1, bF1);
        __builtin_amdgcn_s_setprio(0);

        // ---- P3: quadrant (1,1) ----
        FENCE();
        __builtin_amdgcn_s_barrier();
        FENCE();
        LOAD_AF(Ac, 1);
        if (kt + 2 < NKT) STAGE_HALF(Ag, Ac, 0, kt + 2);
        asm volatile("s_waitcnt lgkmcnt(0)" ::: "memory");
        __builtin_amdgcn_sched_barrier(0);
        __builtin_amdgcn_s_setprio(1);
        MFMA_QUAD(1, 1, bF1);
        __builtin_amdgcn_s_setprio(0);

        // ---- P4: quadrant (1,0) ----
        FENCE();
        __builtin_amdgcn_s_barrier();
        FENCE();
        if (kt + 2 < NKT) STAGE_HALF(Bg, Bc, 1, kt + 2);
        __builtin_amdgcn_s_setprio(1);
        MFMA_QUAD(1, 0, bF0);
        __builtin_amdgcn_s_setprio(0);
    }

    // epilogue: bias + store
    float bias_v[4];
#pragma unroll
    for (int g = 0; g < 4; ++g)
        bias_v[g] = bias[n0 + wn * 64 + g * 16 + fr];

    const int row0 = m0 + wm * 128 + (lane >> 4) * 4;
    const int col0 = n0 + wn * 64 + fr;
#pragma unroll
    for (int f = 0; f < 8; ++f)
#pragma unroll
        for (int g = 0; g < 4; ++g)
#pragma unroll
            for (int rr = 0; rr < 4; ++rr)
                out[(size_t)(row0 + f * 16 + rr) * D_OUT + (col0 + g * 16)] =
                    acc[f][g][rr] + bias_v[g];

#undef STAGE_HALF
#undef LOAD_AF
#undef LOAD_BF
#undef MFMA_QUAD
}

// ---------------------------------------------------------------------------
extern "C" void kernel_launch(void* const* d_in, const int* in_sizes, int n_in,
                              void* d_out, int out_size, void* d_ws, size_t ws_size,
                              hipStream_t stream) {
    const float* x    = (const float*)d_in[0];
    const int*   mask = (const int*)d_in[1];
    const float* W    = (const float*)d_in[2];
    const float* bias = (const float*)d_in[3];
    float*       out  = (float*)d_out;

    __bf16* wsA   = (__bf16*)((char*)d_ws + WS_A_OFF);
    __bf16* wsW   = (__bf16*)((char*)d_ws + WS_W_OFF);
    int*    s_arr = (int*)((char*)d_ws + WS_S_OFF);

    mask_sum_kernel<<<dim3(N_BATCH), dim3(256), 0, stream>>>(mask, s_arr);

    convert_kernel<<<dim3(M_DIM + D_OUT), dim3(256), 0, stream>>>(
        x, W, s_arr, wsA, wsW);

    const int grid = (M_DIM / BM) * (D_OUT / BN);  // 64 * 4 = 256
    gemm_kernel<<<dim3(grid), dim3(512), 0, stream>>>(wsA, wsW, bias, out);
}